// Round 8
// baseline (18059.218 us; speedup 1.0000x reference)
//
#include <hip/hip_runtime.h>
#include <cstdint>

typedef short short8  __attribute__((ext_vector_type(8)));
typedef unsigned short ushort4v __attribute__((ext_vector_type(4)));
typedef float floatx4 __attribute__((ext_vector_type(4)));

#define HID    128
#define NB     64
#define TPB    512
#define NBLK   1024          // 65536 / 64
#define TSTEPS 30
#define MU_OFF 5898240       // 65536*30*3

// ws layout (bf16 units): A-fragment-swizzled weight arrays, hi then lo per set
#define L0_SZ  81920         // 512*160  (K-ext: [Whh(128)|Wih0(3)|0(29)])
#define L1_SZ  131072        // 512*256  (K-ext: [Wih1(128)|Whh1(128)])
#define ENC0_HI 0
#define ENC0_LO 81920
#define ENC1_HI 163840
#define ENC1_LO 294912
#define DEC0_HI 425984
#define DEC0_LO 507904
#define DEC1_HI 589824
#define DEC1_LO 720896

// v_rcp_f32 (~1 ulp) instead of the IEEE div chain
__device__ __forceinline__ float sigm(float v){
  return __builtin_amdgcn_rcpf(1.f + __expf(-v));
}
__device__ __forceinline__ float tanh_fast(float v){
  return 2.f*__builtin_amdgcn_rcpf(1.f + __expf(-2.f*v)) - 1.f;
}

__device__ __forceinline__ unsigned short f2bf(float f){
  unsigned u = __float_as_uint(f);
  u = (u + 0x7FFF + ((u>>16)&1)) >> 16;     // RNE; inputs finite
  return (unsigned short)u;
}
__device__ __forceinline__ float bf2f(unsigned short b){
  return __uint_as_float(((unsigned)b)<<16);
}

// ---------------- prep: swizzle weights into A-fragment order, bf16 hi/lo ----
// A-frag element (mt, kt, lane l, jj):  A[mt*16 + (l&15)][kt*32 + ((l>>4)&3)*8 + jj]
// stored at ((mt*KT + kt)*64 + l)*8 + jj   -> consumer does 1 coalesced b128/lane
extern "C" __global__ void __launch_bounds__(256)
prep_frag(const float* __restrict__ eWih0, const float* __restrict__ eWhh0,
          const float* __restrict__ eWih1, const float* __restrict__ eWhh1,
          const float* __restrict__ dWih0, const float* __restrict__ dWhh0,
          const float* __restrict__ dWih1, const float* __restrict__ dWhh1,
          unsigned short* __restrict__ ws)
{
  const int idx = blockIdx.x*256 + threadIdx.x;   // one thread -> one (hi,lo) pair
  int i2, hi_base, lo_base, KT;
  const float* Wa; const float* Wb;
  if (idx < L0_SZ)                { i2=idx;                 hi_base=ENC0_HI; lo_base=ENC0_LO; Wa=eWhh0; Wb=eWih0; KT=5; }
  else if (idx < L0_SZ+L1_SZ)     { i2=idx-L0_SZ;           hi_base=ENC1_HI; lo_base=ENC1_LO; Wa=eWih1; Wb=eWhh1; KT=8; }
  else if (idx < 2*L0_SZ+L1_SZ)   { i2=idx-(L0_SZ+L1_SZ);   hi_base=DEC0_HI; lo_base=DEC0_LO; Wa=dWhh0; Wb=dWih0; KT=5; }
  else                            { i2=idx-(2*L0_SZ+L1_SZ); hi_base=DEC1_HI; lo_base=DEC1_LO; Wa=dWih1; Wb=dWhh1; KT=8; }
  const int jj = i2 & 7, l = (i2>>3)&63, tk = i2>>9;
  const int kt = (KT==5) ? (tk%5) : (tk&7);
  const int mt = (KT==5) ? (tk/5) : (tk>>3);
  const int row = mt*16 + (l&15);
  const int k   = kt*32 + ((l>>4)&3)*8 + jj;
  float w;
  if (KT==5) w = (k<128) ? Wa[row*128+k] : ((k<131) ? Wb[row*3 + (k-128)] : 0.f);
  else       w = (k<128) ? Wa[row*128+k] : Wb[row*128 + (k-128)];
  const unsigned short hi = f2bf(w);
  ws[hi_base + i2] = hi;
  ws[lo_base + i2] = f2bf(w - bf2f(hi));
}

// ------- fused LSTM: NB=64/block, two phase-offset batch groups per wave ----
// Groups: X = rows 0-31, Y = rows 32-63. Every wave serves BOTH groups.
// Each interval = one basic block: mv(one group) with the OTHER group's
// activation slices fused inside the kt-loop -> per-wave MFMA||VALU overlap
// (no cross-wave scheduling assumptions). Wave w owns m-tile g*8+w per gate.
// Encoder, 4 intervals/step:
//   I1: mv0(X,t)   + act1(Y,t-1)      I2: mv0(Y,t) + act0(X,t)
//   I3: mv1(X,t)   + act0(Y,t) +wrx   I4: mv1(Y,t) + act1(X,t)
// Decoder, 5 intervals/step:
//   I1: mv0(X,t)+fc(Y,t-1)  I2: mv0(Y,t)+act0(X,t)  I3: mv1(X,t)+act0(Y,t)
//   I4: mv1(Y,t)+act1(X,t)  I5: fc(X,t)+act1(Y,t)
extern "C" __global__ void __launch_bounds__(TPB, 2)
lstm_mfma(const float* __restrict__ x,
          const unsigned short* __restrict__ wf,
          const float* __restrict__ enc_b0, const float* __restrict__ enc_b1,
          const float* __restrict__ dec_b0, const float* __restrict__ dec_b1,
          const float* __restrict__ fc_W,  const float* __restrict__ fc_b,
          float* __restrict__ out)
{
  // h in B-frag layout: element (n,k) at n*128 + ((k>>3)^(n&7))*8 + (k&7)
  __shared__ unsigned short h0h[NB*128], h0l[NB*128];
  __shared__ unsigned short h1h[NB*128], h1l[NB*128];
  __shared__ unsigned short xbh[NB*8],  xbl[NB*8];   // x / mu feedback, unswizzled
  __shared__ unsigned short fcAh[4*512], fcAl[4*512];// FC weights, A-frag layout
  __shared__ float bias[2048];                        // [enc0|enc1|dec0|dec1]

  const int tid  = threadIdx.x;
  const int w    = tid>>6, l = tid&63;
  const int quad = (l>>4)&3, n15 = l&15, q7 = n15&7;
  const int b0   = blockIdx.x*NB;

  bias[tid]      = enc_b0[tid];
  bias[512+tid]  = enc_b1[tid];
  bias[1024+tid] = dec_b0[tid];
  bias[1536+tid] = dec_b1[tid];
  for (int i=tid;i<NB*128;i+=TPB){ h0h[i]=0; h0l[i]=0; h1h[i]=0; h1l[i]=0; }
  xbh[tid]=0; xbl[tid]=0;                    // NB*8 == 512 == TPB
  if (w < 4){                                // FC weights -> LDS A-frags, kt=w
    short8 vh, vl;
#pragma unroll
    for (int jj=0;jj<8;jj++){
      const float f = (n15<6) ? fc_W[n15*HID + w*32 + quad*8 + jj] : 0.f;
      const unsigned short hi = f2bf(f);
      vh[jj] = (short)hi;
      vl[jj] = (short)f2bf(f - bf2f(hi));
    }
    *(short8*)(fcAh + (w*64+l)*8) = vh;
    *(short8*)(fcAl + (w*64+l)*8) = vl;
  }
  float myfcb[4];
#pragma unroll
  for (int r=0;r<4;r++){
    const int oi = quad*4 + r;
    myfcb[r] = (oi<6) ? fc_b[oi] : 0.f;
  }
  __syncthreads();

  auto write_x = [&](int t){
    if (tid < 192){
      const int n = tid & 63, c = tid >> 6;
      const float v = x[(size_t)(b0+n)*90 + t*3 + c];
      const unsigned short hi = f2bf(v);
      xbh[n*8+c] = hi; xbl[n*8+c] = f2bf(v - bf2f(hi));
    }
  };
  write_x(0);
  __syncthreads();

  floatx4 accX[4][2], accY[4][2];    // [gate][nt]; 32 AGPR each
  float c0X[2][4], c1X[2][4], c0Y[2][4], c1Y[2][4];   // [nt][r]
#pragma unroll
  for (int nt=0;nt<2;nt++)
#pragma unroll
    for (int r=0;r<4;r++){ c0X[nt][r]=0.f; c1X[nt][r]=0.f; c0Y[nt][r]=0.f; c1Y[nt][r]=0.f; }

  auto zacc = [&](floatx4 (&a)[4][2]){
    const floatx4 z = {0.f,0.f,0.f,0.f};
#pragma unroll
    for (int g=0;g<4;g++){ a[g][0]=z; a[g][1]=z; }
  };

  // one kt-block: acc += A(kt) * B(kb)   (24 MFMA; per-acc order hh->hl->lh)
  auto mv_kt = [&](floatx4 (&acc)[4][2],
                   const unsigned short* __restrict__ Ahi,
                   const unsigned short* __restrict__ Alo,
                   int KT, int kt, int kb,
                   const unsigned short* Bh, const unsigned short* Bl, int rbm){
    const int bo = (((kb*4+quad)^q7)<<3);
    const short8 bh0 = *(const short8*)(Bh + (rbm     + n15)*128 + bo);
    const short8 bh1 = *(const short8*)(Bh + (rbm+16  + n15)*128 + bo);
    const short8 bl0 = *(const short8*)(Bl + (rbm     + n15)*128 + bo);
    const short8 bl1 = *(const short8*)(Bl + (rbm+16  + n15)*128 + bo);
    short8 ah[4], al[4];
#pragma unroll
    for (int g=0; g<4; ++g){
      const int ao = (((g*8+w)*KT + kt)*64 + l)*8;
      ah[g] = *(const short8*)(Ahi + ao);
      al[g] = *(const short8*)(Alo + ao);
    }
#pragma unroll
    for (int g=0; g<4; ++g){
      acc[g][0] = __builtin_amdgcn_mfma_f32_16x16x32_bf16(ah[g], bh0, acc[g][0],0,0,0);
      acc[g][1] = __builtin_amdgcn_mfma_f32_16x16x32_bf16(ah[g], bh1, acc[g][1],0,0,0);
    }
#pragma unroll
    for (int g=0; g<4; ++g){
      acc[g][0] = __builtin_amdgcn_mfma_f32_16x16x32_bf16(ah[g], bl0, acc[g][0],0,0,0);
      acc[g][1] = __builtin_amdgcn_mfma_f32_16x16x32_bf16(ah[g], bl1, acc[g][1],0,0,0);
    }
#pragma unroll
    for (int g=0; g<4; ++g){
      acc[g][0] = __builtin_amdgcn_mfma_f32_16x16x32_bf16(al[g], bh0, acc[g][0],0,0,0);
      acc[g][1] = __builtin_amdgcn_mfma_f32_16x16x32_bf16(al[g], bh1, acc[g][1],0,0,0);
    }
  };

  // layer-0 x-kt (kt=4, KT=5): B from xbuf; real data k<131, quad 0 only
  auto mvx_kt = [&](floatx4 (&acc)[4][2],
                    const unsigned short* __restrict__ Ahi,
                    const unsigned short* __restrict__ Alo, int rbm){
    const short8 z8 = {0,0,0,0,0,0,0,0};
    short8 bh0=z8, bh1=z8, bl0=z8, bl1=z8;
    if (quad==0){
      bh0 = *(const short8*)(xbh + (rbm     + n15)*8);
      bh1 = *(const short8*)(xbh + (rbm+16  + n15)*8);
      bl0 = *(const short8*)(xbl + (rbm     + n15)*8);
      bl1 = *(const short8*)(xbl + (rbm+16  + n15)*8);
    }
    short8 ah[4], al[4];
#pragma unroll
    for (int g=0; g<4; ++g){
      const int ao = (((g*8+w)*5 + 4)*64 + l)*8;
      ah[g] = *(const short8*)(Ahi + ao);
      al[g] = *(const short8*)(Alo + ao);
    }
#pragma unroll
    for (int g=0; g<4; ++g){
      acc[g][0] = __builtin_amdgcn_mfma_f32_16x16x32_bf16(ah[g], bh0, acc[g][0],0,0,0);
      acc[g][1] = __builtin_amdgcn_mfma_f32_16x16x32_bf16(ah[g], bh1, acc[g][1],0,0,0);
    }
#pragma unroll
    for (int g=0; g<4; ++g){
      acc[g][0] = __builtin_amdgcn_mfma_f32_16x16x32_bf16(al[g], bh0, acc[g][0],0,0,0);
      acc[g][1] = __builtin_amdgcn_mfma_f32_16x16x32_bf16(al[g], bh1, acc[g][1],0,0,0);
    }
#pragma unroll
    for (int g=0; g<4; ++g){
      acc[g][0] = __builtin_amdgcn_mfma_f32_16x16x32_bf16(ah[g], bl0, acc[g][0],0,0,0);
      acc[g][1] = __builtin_amdgcn_mfma_f32_16x16x32_bf16(ah[g], bl1, acc[g][1],0,0,0);
    }
  };
  // NOTE: mvx order per acc is hh, lh(=al*bh), hl to keep hh->hl->lh per R2?
  // R2 order per kt was hh, hl(=ah*bl), lh(=al*bh). Kept EXACT in mv_kt; in
  // mvx the middle/last sections were swapped above — fix to match R2:
  // (handled: see mvx_kt2 usage below)

  // exact-R2-order variant of the x-kt
  auto mvx_kt2 = [&](floatx4 (&acc)[4][2],
                     const unsigned short* __restrict__ Ahi,
                     const unsigned short* __restrict__ Alo, int rbm){
    const short8 z8 = {0,0,0,0,0,0,0,0};
    short8 bh0=z8, bh1=z8, bl0=z8, bl1=z8;
    if (quad==0){
      bh0 = *(const short8*)(xbh + (rbm     + n15)*8);
      bh1 = *(const short8*)(xbh + (rbm+16  + n15)*8);
      bl0 = *(const short8*)(xbl + (rbm     + n15)*8);
      bl1 = *(const short8*)(xbl + (rbm+16  + n15)*8);
    }
    short8 ah[4], al[4];
#pragma unroll
    for (int g=0; g<4; ++g){
      const int ao = (((g*8+w)*5 + 4)*64 + l)*8;
      ah[g] = *(const short8*)(Ahi + ao);
      al[g] = *(const short8*)(Alo + ao);
    }
#pragma unroll
    for (int g=0; g<4; ++g){
      acc[g][0] = __builtin_amdgcn_mfma_f32_16x16x32_bf16(ah[g], bh0, acc[g][0],0,0,0);
      acc[g][1] = __builtin_amdgcn_mfma_f32_16x16x32_bf16(ah[g], bh1, acc[g][1],0,0,0);
    }
#pragma unroll
    for (int g=0; g<4; ++g){
      acc[g][0] = __builtin_amdgcn_mfma_f32_16x16x32_bf16(ah[g], bl0, acc[g][0],0,0,0);
      acc[g][1] = __builtin_amdgcn_mfma_f32_16x16x32_bf16(ah[g], bl1, acc[g][1],0,0,0);
    }
#pragma unroll
    for (int g=0; g<4; ++g){
      acc[g][0] = __builtin_amdgcn_mfma_f32_16x16x32_bf16(al[g], bh0, acc[g][0],0,0,0);
      acc[g][1] = __builtin_amdgcn_mfma_f32_16x16x32_bf16(al[g], bh1, acc[g][1],0,0,0);
    }
  };

  // one activation slice: elements [nt=0,1][r=q] of the act-group
  auto act_q = [&](int q, floatx4 (&aa)[4][2], float (&ca)[2][4], int boff,
                   ushort4v (&ph)[2], ushort4v (&pl)[2]){
#pragma unroll
    for (int nt=0; nt<2; ++nt){
      const int j = w*16 + quad*4 + q;
      const float i_ = sigm(aa[0][nt][q]      + bias[boff       + j]);
      const float f_ = sigm(aa[1][nt][q]      + bias[boff + 128 + j]);
      const float g_ = tanh_fast(aa[2][nt][q] + bias[boff + 256 + j]);
      const float o_ = sigm(aa[3][nt][q]      + bias[boff + 384 + j]);
      const float c  = f_*ca[nt][q] + i_*g_;
      ca[nt][q] = c;
      const float h  = o_*tanh_fast(c);
      const unsigned short hi = f2bf(h);
      ph[nt][q] = hi;
      pl[nt][q] = f2bf(h - bf2f(hi));
    }
  };

  auto act_wr = [&](ushort4v (&ph)[2], ushort4v (&pl)[2],
                    unsigned short* Hh, unsigned short* Hl, int rba){
    const int jb = w*2 + (quad>>1);
#pragma unroll
    for (int nt=0; nt<2; ++nt){
      const int n = rba + nt*16 + n15;
      const int base = n*128 + ((jb ^ (n&7))<<3) + ((quad&1)<<2);
      *(ushort4v*)(Hh + base) = ph[nt];
      *(ushort4v*)(Hl + base) = pl[nt];
    }
  };

  // interval: mv layer-0 of group rbm, act slices of the other group fused
  auto iv_mv0 = [&](floatx4 (&am)[4][2], int rbm,
                    const unsigned short* WHI, const unsigned short* WLO,
                    bool doact, floatx4 (&aa)[4][2], float (&ca)[2][4], int boff,
                    unsigned short* Hh, unsigned short* Hl, int rba){
    ushort4v ph[2], pl[2];
#pragma unroll
    for (int kt=0; kt<4; ++kt){
      mv_kt(am, WHI, WLO, 5, kt, kt, h0h, h0l, rbm);
      if (doact) act_q(kt, aa, ca, boff, ph, pl);
    }
    mvx_kt2(am, WHI, WLO, rbm);
    if (doact) act_wr(ph, pl, Hh, Hl, rba);
  };

  // interval: mv layer-1 (h1-half then h0-half), act slices fused in first half
  auto iv_mv1 = [&](floatx4 (&am)[4][2], int rbm,
                    const unsigned short* WHI, const unsigned short* WLO,
                    bool doact, floatx4 (&aa)[4][2], float (&ca)[2][4], int boff,
                    unsigned short* Hh, unsigned short* Hl, int rba){
    ushort4v ph[2], pl[2];
#pragma unroll
    for (int kt=0; kt<4; ++kt){
      mv_kt(am, WHI, WLO, 8, kt+4, kt, h1h, h1l, rbm);
      if (doact) act_q(kt, aa, ca, boff, ph, pl);
    }
    if (doact) act_wr(ph, pl, Hh, Hl, rba);
#pragma unroll
    for (int kt=0; kt<4; ++kt)
      mv_kt(am, WHI, WLO, 8, kt, kt, h0h, h0l, rbm);
  };

  // plain full activation (epilogues / unpaired)
  auto act_full = [&](floatx4 (&aa)[4][2], float (&ca)[2][4], int boff,
                      unsigned short* Hh, unsigned short* Hl, int rba){
    ushort4v ph[2], pl[2];
#pragma unroll
    for (int q=0; q<4; ++q) act_q(q, aa, ca, boff, ph, pl);
    act_wr(ph, pl, Hh, Hl, rba);
  };

  // FC head via MFMA on h1 rows of group rba (waves 0-1, 16 rows each)
  auto fc = [&](int rba, int t){
    if (w < 2){
      floatx4 fa = {0.f,0.f,0.f,0.f};
#pragma unroll
      for (int kt=0;kt<4;kt++){
        const short8 ah = *(const short8*)(fcAh + (kt*64+l)*8);
        const short8 al = *(const short8*)(fcAl + (kt*64+l)*8);
        const int bo = (((kt*4+quad)^q7)<<3);
        const int ro = (rba + w*16 + n15)*128 + bo;
        const short8 bh = *(const short8*)(h1h + ro);
        const short8 bl = *(const short8*)(h1l + ro);
        fa = __builtin_amdgcn_mfma_f32_16x16x32_bf16(ah, bh, fa,0,0,0);
        fa = __builtin_amdgcn_mfma_f32_16x16x32_bf16(ah, bl, fa,0,0,0);
        fa = __builtin_amdgcn_mfma_f32_16x16x32_bf16(al, bh, fa,0,0,0);
      }
      const int n = rba + w*16 + n15;
      const size_t off = (size_t)(b0+n)*90 + (size_t)t*3;
      if (quad == 0){
#pragma unroll
        for (int r=0;r<4;r++){
          const float s = fa[r] + myfcb[r];
          if (r < 3){
            out[off + r] = s;                        // mu
            const unsigned short hi = f2bf(s);       // feed mu back as next x
            xbh[n*8+r] = hi; xbl[n*8+r] = f2bf(s - bf2f(hi));
          } else {
            out[MU_OFF + off] = s;                   // logvar[0]
          }
        }
      } else if (quad == 1){
#pragma unroll
        for (int r=0;r<2;r++)
          out[MU_OFF + off + 1 + r] = fa[r] + myfcb[r];  // logvar[1,2]
      }
    }
  };

  // ---------------- encoder ----------------
#pragma unroll 1
  for (int t=0; t<TSTEPS; ++t){
    // I1: mv0(X,t) + act1(Y,t-1)
    zacc(accX);
    iv_mv0(accX, 0, wf+ENC0_HI, wf+ENC0_LO, t>0, accY, c1Y, 512, h1h, h1l, 32);
    __syncthreads();
    // I2: mv0(Y,t) + act0(X,t)
    zacc(accY);
    iv_mv0(accY, 32, wf+ENC0_HI, wf+ENC0_LO, true, accX, c0X, 0, h0h, h0l, 0);
    __syncthreads();
    // I3: mv1(X,t) + act0(Y,t); write_x(t+1)
    zacc(accX);
    iv_mv1(accX, 0, wf+ENC1_HI, wf+ENC1_LO, true, accY, c0Y, 0, h0h, h0l, 32);
    if (t+1 < TSTEPS) write_x(t+1);
    __syncthreads();
    // I4: mv1(Y,t) + act1(X,t)
    zacc(accY);
    iv_mv1(accY, 32, wf+ENC1_HI, wf+ENC1_LO, true, accX, c1X, 512, h1h, h1l, 0);
    __syncthreads();
  }
  // epilogue: act1(Y,29)
  act_full(accY, c1Y, 512, h1h, h1l, 32);
  __syncthreads();
  // xbuf still holds x[:,29,:] == decoder's initial input

  // ---------------- decoder ----------------
#pragma unroll 1
  for (int t=0; t<TSTEPS; ++t){
    // I1: mv0(X,t) + fc(Y,t-1)
    zacc(accX);
    iv_mv0(accX, 0, wf+DEC0_HI, wf+DEC0_LO, false, accY, c1Y, 1536, h1h, h1l, 32);
    if (t > 0) fc(32, t-1);
    __syncthreads();
    // I2: mv0(Y,t) + act0(X,t)
    zacc(accY);
    iv_mv0(accY, 32, wf+DEC0_HI, wf+DEC0_LO, true, accX, c0X, 1024, h0h, h0l, 0);
    __syncthreads();
    // I3: mv1(X,t) + act0(Y,t)
    zacc(accX);
    iv_mv1(accX, 0, wf+DEC1_HI, wf+DEC1_LO, true, accY, c0Y, 1024, h0h, h0l, 32);
    __syncthreads();
    // I4: mv1(Y,t) + act1(X,t)
    zacc(accY);
    iv_mv1(accY, 32, wf+DEC1_HI, wf+DEC1_LO, true, accX, c1X, 1536, h1h, h1l, 0);
    __syncthreads();
    // I5: fc(X,t) + act1(Y,t)
    fc(0, t);
    act_full(accY, c1Y, 1536, h1h, h1l, 32);
    __syncthreads();
  }
  // epilogue: fc(Y,29)
  fc(32, TSTEPS-1);
}

extern "C" void kernel_launch(void* const* d_in, const int* in_sizes, int n_in,
                              void* d_out, int out_size, void* d_ws, size_t ws_size,
                              hipStream_t stream) {
  const float* x        = (const float*)d_in[0];
  const float* enc_Wih0 = (const float*)d_in[1];
  const float* enc_Whh0 = (const float*)d_in[2];
  const float* enc_b0   = (const float*)d_in[3];
  const float* enc_Wih1 = (const float*)d_in[4];
  const float* enc_Whh1 = (const float*)d_in[5];
  const float* enc_b1   = (const float*)d_in[6];
  const float* dec_Wih0 = (const float*)d_in[7];
  const float* dec_Whh0 = (const float*)d_in[8];
  const float* dec_b0   = (const float*)d_in[9];
  const float* dec_Wih1 = (const float*)d_in[10];
  const float* dec_Whh1 = (const float*)d_in[11];
  const float* dec_b1   = (const float*)d_in[12];
  const float* fc_W     = (const float*)d_in[13];
  const float* fc_b     = (const float*)d_in[14];
  unsigned short* ws = (unsigned short*)d_ws;
  float* out = (float*)d_out;

  // 425,984 (hi,lo) pairs -> exactly 1664 blocks of 256
  prep_frag<<<1664, 256, 0, stream>>>(
      enc_Wih0, enc_Whh0, enc_Wih1, enc_Whh1,
      dec_Wih0, dec_Whh0, dec_Wih1, dec_Whh1, ws);

  lstm_mfma<<<NBLK, TPB, 0, stream>>>(
      x, ws, enc_b0, enc_b1, dec_b0, dec_b1, fc_W, fc_b, out);
}

// Round 9
// 3314.964 us; speedup vs baseline: 5.4478x; 5.4478x over previous
//
#include <hip/hip_runtime.h>
#include <cstdint>

typedef short short8  __attribute__((ext_vector_type(8)));
typedef unsigned short ushort4v __attribute__((ext_vector_type(4)));
typedef float floatx4 __attribute__((ext_vector_type(4)));

#define HID    128
#define NB     32
#define TPB    512
#define NBLK   2048          // 65536 / 32
#define TSTEPS 30
#define MU_OFF 5898240       // 65536*30*3

// ws layout (bf16 units): A-fragment-swizzled weight arrays, hi then lo per set
// (lo arrays still produced by prep; the LSTM kernel reads only the hi set)
#define L0_SZ  81920         // 512*160  (K-ext: [Whh(128)|Wih0(3)|0(29)])
#define L1_SZ  131072        // 512*256  (K-ext: [Wih1(128)|Whh1(128)])
#define ENC0_HI 0
#define ENC0_LO 81920
#define ENC1_HI 163840
#define ENC1_LO 294912
#define DEC0_HI 425984
#define DEC0_LO 507904
#define DEC1_HI 589824
#define DEC1_LO 720896

// v_rcp_f32 (~1 ulp) instead of the IEEE div chain
__device__ __forceinline__ float sigm(float v){
  return __builtin_amdgcn_rcpf(1.f + __expf(-v));
}
__device__ __forceinline__ float tanh_fast(float v){
  return 2.f*__builtin_amdgcn_rcpf(1.f + __expf(-2.f*v)) - 1.f;
}

__device__ __forceinline__ unsigned short f2bf(float f){
  unsigned u = __float_as_uint(f);
  u = (u + 0x7FFF + ((u>>16)&1)) >> 16;     // RNE; inputs finite
  return (unsigned short)u;
}
__device__ __forceinline__ float bf2f(unsigned short b){
  return __uint_as_float(((unsigned)b)<<16);
}

// ---------------- prep: swizzle weights into A-fragment order, bf16 hi/lo ----
// A-frag element (mt, kt, lane l, jj):  A[mt*16 + (l&15)][kt*32 + ((l>>4)&3)*8 + jj]
// stored at ((mt*KT + kt)*64 + l)*8 + jj   -> consumer does 1 coalesced b128/lane
extern "C" __global__ void __launch_bounds__(256)
prep_frag(const float* __restrict__ eWih0, const float* __restrict__ eWhh0,
          const float* __restrict__ eWih1, const float* __restrict__ eWhh1,
          const float* __restrict__ dWih0, const float* __restrict__ dWhh0,
          const float* __restrict__ dWih1, const float* __restrict__ dWhh1,
          unsigned short* __restrict__ ws)
{
  const int idx = blockIdx.x*256 + threadIdx.x;   // one thread -> one (hi,lo) pair
  int i2, hi_base, lo_base, KT;
  const float* Wa; const float* Wb;
  if (idx < L0_SZ)                { i2=idx;                 hi_base=ENC0_HI; lo_base=ENC0_LO; Wa=eWhh0; Wb=eWih0; KT=5; }
  else if (idx < L0_SZ+L1_SZ)     { i2=idx-L0_SZ;           hi_base=ENC1_HI; lo_base=ENC1_LO; Wa=eWih1; Wb=eWhh1; KT=8; }
  else if (idx < 2*L0_SZ+L1_SZ)   { i2=idx-(L0_SZ+L1_SZ);   hi_base=DEC0_HI; lo_base=DEC0_LO; Wa=dWhh0; Wb=dWih0; KT=5; }
  else                            { i2=idx-(2*L0_SZ+L1_SZ); hi_base=DEC1_HI; lo_base=DEC1_LO; Wa=dWih1; Wb=dWhh1; KT=8; }
  const int jj = i2 & 7, l = (i2>>3)&63, tk = i2>>9;
  const int kt = (KT==5) ? (tk%5) : (tk&7);
  const int mt = (KT==5) ? (tk/5) : (tk>>3);
  const int row = mt*16 + (l&15);
  const int k   = kt*32 + ((l>>4)&3)*8 + jj;
  float w;
  if (KT==5) w = (k<128) ? Wa[row*128+k] : ((k<131) ? Wb[row*3 + (k-128)] : 0.f);
  else       w = (k<128) ? Wa[row*128+k] : Wb[row*128 + (k-128)];
  const unsigned short hi = f2bf(w);
  ws[hi_base + i2] = hi;
  ws[lo_base + i2] = f2bf(w - bf2f(hi));
}

// ------- fused LSTM: NB=32/block, 8 waves, 2 BLOCKS PER CU ------------------
// launch_bounds(512,4): 4 waves/SIMD = 2 independent blocks co-resident; the
// blocks drift out of phase naturally, so one block's mv (MFMA) overlaps the
// other's act (VALU) without any source-level scheduling (m114 co-issue).
// Weights: single bf16 (hi only) -> halves L2 traffic, 2 MFMA combos (hh, hl).
// h stays bf16 hi/lo. Wave w owns m-tile g*8+w per gate (j in [16w,16w+16)).
extern "C" __global__ void __launch_bounds__(TPB, 4)
lstm_mfma(const float* __restrict__ x,
          const unsigned short* __restrict__ wf,
          const float* __restrict__ enc_b0, const float* __restrict__ enc_b1,
          const float* __restrict__ dec_b0, const float* __restrict__ dec_b1,
          const float* __restrict__ fc_W,  const float* __restrict__ fc_b,
          float* __restrict__ out)
{
  // h in B-frag layout: element (n,k) at n*128 + ((k>>3)^(n&7))*8 + (k&7)
  __shared__ unsigned short h0h[NB*128], h0l[NB*128];
  __shared__ unsigned short h1h[NB*128], h1l[NB*128];
  __shared__ unsigned short xbh[NB*8],  xbl[NB*8];   // x / mu feedback, unswizzled
  __shared__ unsigned short fcAh[4*512], fcAl[4*512];// FC weights, A-frag layout
  __shared__ float bias[1024];                        // current phase: [b0 | b1]

  const int tid  = threadIdx.x;
  const int w    = tid>>6, l = tid&63;
  const int quad = (l>>4)&3, n15 = l&15, q7 = n15&7;
  const int b0   = blockIdx.x*NB;

  bias[tid]       = enc_b0[tid];
  bias[512+tid-512+512] = bias[512+tid-512+512]; // no-op guard (kept simple below)
  bias[tid < 512 ? tid : tid] = enc_b0[tid];     // (tid always <512)
  // simple, explicit:
  bias[tid] = enc_b0[tid];
  // second half staged by same threads:
  // (bias has 1024 floats; 512 threads -> two writes)
  bias[512 + tid] = enc_b1[tid];
  for (int i=tid;i<NB*128;i+=TPB){ h0h[i]=0; h0l[i]=0; h1h[i]=0; h1l[i]=0; }
  if (tid < NB*8){ xbh[tid]=0; xbl[tid]=0; }          // NB*8 == 256
  if (w < 4){                                // FC weights -> LDS A-frags, kt=w
    short8 vh, vl;
#pragma unroll
    for (int jj=0;jj<8;jj++){
      const float f = (n15<6) ? fc_W[n15*HID + w*32 + quad*8 + jj] : 0.f;
      const unsigned short hi = f2bf(f);
      vh[jj] = (short)hi;
      vl[jj] = (short)f2bf(f - bf2f(hi));
    }
    *(short8*)(fcAh + (w*64+l)*8) = vh;
    *(short8*)(fcAl + (w*64+l)*8) = vl;
  }
  float myfcb[4];
#pragma unroll
  for (int r=0;r<4;r++){
    const int oi = quad*4 + r;
    myfcb[r] = (oi<6) ? fc_b[oi] : 0.f;
  }
  __syncthreads();

  auto write_x = [&](int t){
    if (tid < 96){
      const int n = tid & 31, c = tid >> 5;
      const float v = x[(size_t)(b0+n)*90 + t*3 + c];
      const unsigned short hi = f2bf(v);
      xbh[n*8+c] = hi; xbl[n*8+c] = f2bf(v - bf2f(hi));
    }
  };
  write_x(0);
  __syncthreads();

  floatx4 acc[4][2];                 // [gate][nt]; 32 regs
  float c0[2][4], c1[2][4];          // [nt][r]
#pragma unroll
  for (int nt=0;nt<2;nt++)
#pragma unroll
    for (int r=0;r<4;r++){ c0[nt][r]=0.f; c1[nt][r]=0.f; }

  auto zacc = [&]{
    const floatx4 z = {0.f,0.f,0.f,0.f};
#pragma unroll
    for (int g=0;g<4;g++){ acc[g][0]=z; acc[g][1]=z; }
  };

  // acc += A(kt range, single bf16) * B(hi/lo)   combos: hh then hl per acc
  auto mv = [&](const unsigned short* __restrict__ Ahi, int KT,
                int k0, int k1, int kboff,
                const unsigned short* Bh, const unsigned short* Bl){
#pragma unroll 1
    for (int kt=k0; kt<k1; ++kt){
      const int bo = ((((kt-kboff)*4+quad)^q7)<<3);
      short8 bh[2], bl[2];
#pragma unroll
      for (int nt=0;nt<2;nt++){
        const int ro = (nt*16+n15)*128 + bo;
        bh[nt] = *(const short8*)(Bh + ro);
        bl[nt] = *(const short8*)(Bl + ro);
      }
      short8 ah[4];
#pragma unroll
      for (int g=0;g<4;g++){
        const int ao = (((g*8+w)*KT + kt)*64 + l)*8;
        ah[g] = *(const short8*)(Ahi + ao);
      }
#pragma unroll
      for (int g=0;g<4;g++){
        acc[g][0] = __builtin_amdgcn_mfma_f32_16x16x32_bf16(ah[g], bh[0], acc[g][0],0,0,0);
        acc[g][1] = __builtin_amdgcn_mfma_f32_16x16x32_bf16(ah[g], bh[1], acc[g][1],0,0,0);
      }
#pragma unroll
      for (int g=0;g<4;g++){
        acc[g][0] = __builtin_amdgcn_mfma_f32_16x16x32_bf16(ah[g], bl[0], acc[g][0],0,0,0);
        acc[g][1] = __builtin_amdgcn_mfma_f32_16x16x32_bf16(ah[g], bl[1], acc[g][1],0,0,0);
      }
    }
  };

  // kt=4 of layer 0: B comes from xbuf (k=128..135; real data k<131, quad 0 only)
  auto mv_x = [&](const unsigned short* __restrict__ Ahi){
    const short8 z8 = {0,0,0,0,0,0,0,0};
    short8 bh[2]={z8,z8}, bl[2]={z8,z8};
    if (quad==0){
#pragma unroll
      for (int nt=0;nt<2;nt++){
        const int ro = (nt*16+n15)*8;
        bh[nt] = *(const short8*)(xbh + ro);
        bl[nt] = *(const short8*)(xbl + ro);
      }
    }
    short8 ah[4];
#pragma unroll
    for (int g=0;g<4;g++){
      const int ao = (((g*8+w)*5 + 4)*64 + l)*8;
      ah[g] = *(const short8*)(Ahi + ao);
    }
#pragma unroll
    for (int g=0;g<4;g++){
      acc[g][0] = __builtin_amdgcn_mfma_f32_16x16x32_bf16(ah[g], bh[0], acc[g][0],0,0,0);
      acc[g][1] = __builtin_amdgcn_mfma_f32_16x16x32_bf16(ah[g], bh[1], acc[g][1],0,0,0);
    }
#pragma unroll
    for (int g=0;g<4;g++){
      acc[g][0] = __builtin_amdgcn_mfma_f32_16x16x32_bf16(ah[g], bl[0], acc[g][0],0,0,0);
      acc[g][1] = __builtin_amdgcn_mfma_f32_16x16x32_bf16(ah[g], bl[1], acc[g][1],0,0,0);
    }
  };

  // activations in-register; barrier, then packed b64 h-writes
  auto cell_update = [&](float (&cst)[2][4], int boff,
                         unsigned short* Hh, unsigned short* Hl){
    float hv[2][4];
#pragma unroll
    for (int nt=0;nt<2;nt++)
#pragma unroll
      for (int r=0;r<4;r++){
        const int j = w*16 + quad*4 + r;
        const float i_ = sigm(acc[0][nt][r]      + bias[boff       + j]);
        const float f_ = sigm(acc[1][nt][r]      + bias[boff + 128 + j]);
        const float g_ = tanh_fast(acc[2][nt][r] + bias[boff + 256 + j]);
        const float o_ = sigm(acc[3][nt][r]      + bias[boff + 384 + j]);
        const float c  = f_*cst[nt][r] + i_*g_;
        cst[nt][r] = c;
        hv[nt][r]  = o_*tanh_fast(c);
      }
    __syncthreads();                 // all waves done READING old h
#pragma unroll
    for (int nt=0;nt<2;nt++){
      const int jb = w*2 + (quad>>1);              // j>>3
      const int n  = nt*16 + n15;
      const int base = n*128 + ((jb ^ (n&7))<<3) + ((quad&1)<<2);
      ushort4v ph, pl;
#pragma unroll
      for (int r=0;r<4;r++){
        const unsigned short hi = f2bf(hv[nt][r]);
        ph[r] = hi;
        pl[r] = f2bf(hv[nt][r] - bf2f(hi));
      }
      *(ushort4v*)(Hh + base) = ph;                // ds_write_b64
      *(ushort4v*)(Hl + base) = pl;
    }
  };

  // -------------------- encoder --------------------
#pragma unroll 1
  for (int t=0; t<TSTEPS; ++t){
    zacc();
    mv  (wf+ENC0_HI, 5, 0, 4, 0, h0h, h0l);
    mv_x(wf+ENC0_HI);
    cell_update(c0, 0, h0h, h0l);
    if (t+1 < TSTEPS) write_x(t+1);      // xbuf disjoint from h writes
    __syncthreads();
    zacc();
    mv(wf+ENC1_HI, 8, 0, 4, 0, h0h, h0l);
    mv(wf+ENC1_HI, 8, 4, 8, 4, h1h, h1l);
    cell_update(c1, 512, h1h, h1l);
    __syncthreads();
  }
  // xbuf still holds x[:,29,:] == decoder's initial input

  // ---- phase switch: dec biases into LDS ----
  bias[tid]       = dec_b0[tid];
  bias[512 + tid] = dec_b1[tid];
  __syncthreads();

  // -------------------- decoder --------------------
#pragma unroll 1
  for (int t=0; t<TSTEPS; ++t){
    zacc();
    mv  (wf+DEC0_HI, 5, 0, 4, 0, h0h, h0l);
    mv_x(wf+DEC0_HI);
    cell_update(c0, 0, h0h, h0l);
    __syncthreads();
    zacc();
    mv(wf+DEC1_HI, 8, 0, 4, 0, h0h, h0l);
    mv(wf+DEC1_HI, 8, 4, 8, 4, h1h, h1l);
    cell_update(c1, 512, h1h, h1l);
    __syncthreads();

    // FC head via MFMA: waves 0-1 handle rows n = w*16 .. w*16+15
    // C layout: col=lane&15 -> n, row=quad*4+r -> oi (0..5 used)
    if (w < 2){
      floatx4 fa = {0.f,0.f,0.f,0.f};
#pragma unroll
      for (int kt=0;kt<4;kt++){
        const short8 ah = *(const short8*)(fcAh + (kt*64+l)*8);
        const short8 al = *(const short8*)(fcAl + (kt*64+l)*8);
        const int bo = (((kt*4+quad)^q7)<<3);
        const int ro = (w*16+n15)*128 + bo;
        const short8 bh = *(const short8*)(h1h + ro);
        const short8 bl = *(const short8*)(h1l + ro);
        fa = __builtin_amdgcn_mfma_f32_16x16x32_bf16(ah, bh, fa,0,0,0);
        fa = __builtin_amdgcn_mfma_f32_16x16x32_bf16(ah, bl, fa,0,0,0);
        fa = __builtin_amdgcn_mfma_f32_16x16x32_bf16(al, bh, fa,0,0,0);
      }
      const int n = w*16 + n15;
      const size_t off = (size_t)(b0+n)*90 + (size_t)t*3;
      if (quad == 0){
#pragma unroll
        for (int r=0;r<4;r++){
          const float s = fa[r] + myfcb[r];
          if (r < 3){
            out[off + r] = s;                         // mu
            const unsigned short hi = f2bf(s);        // feed mu back as next x
            xbh[n*8+r] = hi; xbl[n*8+r] = f2bf(s - bf2f(hi));
          } else {
            out[MU_OFF + off] = s;                    // logvar[0]
          }
        }
      } else if (quad == 1){
#pragma unroll
        for (int r=0;r<2;r++)
          out[MU_OFF + off + 1 + r] = fa[r] + myfcb[r];  // logvar[1,2]
      }
    }
    __syncthreads();
  }
}

extern "C" void kernel_launch(void* const* d_in, const int* in_sizes, int n_in,
                              void* d_out, int out_size, void* d_ws, size_t ws_size,
                              hipStream_t stream) {
  const float* x        = (const float*)d_in[0];
  const float* enc_Wih0 = (const float*)d_in[1];
  const float* enc_Whh0 = (const float*)d_in[2];
  const float* enc_b0   = (const float*)d_in[3];
  const float* enc_Wih1 = (const float*)d_in[4];
  const float* enc_Whh1 = (const float*)d_in[5];
  const float* enc_b1   = (const float*)d_in[6];
  const float* dec_Wih0 = (const float*)d_in[7];
  const float* dec_Whh0 = (const float*)d_in[8];
  const float* dec_b0   = (const float*)d_in[9];
  const float* dec_Wih1 = (const float*)d_in[10];
  const float* dec_Whh1 = (const float*)d_in[11];
  const float* dec_b1   = (const float*)d_in[12];
  const float* fc_W     = (const float*)d_in[13];
  const float* fc_b     = (const float*)d_in[14];
  unsigned short* ws = (unsigned short*)d_ws;
  float* out = (float*)d_out;

  // 425,984 (hi,lo) pairs -> exactly 1664 blocks of 256
  prep_frag<<<1664, 256, 0, stream>>>(
      enc_Wih0, enc_Whh0, enc_Wih1, enc_Whh1,
      dec_Wih0, dec_Whh0, dec_Wih1, dec_Whh1, ws);

  lstm_mfma<<<NBLK, TPB, 0, stream>>>(
      x, ws, enc_b0, enc_b1, dec_b0, dec_b1, fc_W, fc_b, out);
}

// Round 10
// 3271.904 us; speedup vs baseline: 5.5195x; 1.0132x over previous
//
#include <hip/hip_runtime.h>
#include <cstdint>

typedef short short8  __attribute__((ext_vector_type(8)));
typedef unsigned short ushort4v __attribute__((ext_vector_type(4)));
typedef float floatx4 __attribute__((ext_vector_type(4)));

#define HID    128
#define NB     32
#define TPB    512
#define NBLK   2048          // 65536 / 32
#define TSTEPS 30
#define MU_OFF 5898240       // 65536*30*3
#define HSZ    4096          // NB*128: one h parity buffer (bf16 units)

// ws layout (bf16 units): A-fragment-swizzled weight arrays, hi then lo per set
// (lo arrays still produced by prep; the LSTM kernel reads only the hi set)
#define L0_SZ  81920         // 512*160  (K-ext: [Whh(128)|Wih0(3)|0(29)])
#define L1_SZ  131072        // 512*256  (K-ext: [Wih1(128)|Whh1(128)])
#define ENC0_HI 0
#define ENC0_LO 81920
#define ENC1_HI 163840
#define ENC1_LO 294912
#define DEC0_HI 425984
#define DEC0_LO 507904
#define DEC1_HI 589824
#define DEC1_LO 720896

// v_rcp_f32 (~1 ulp) instead of the IEEE div chain
__device__ __forceinline__ float sigm(float v){
  return __builtin_amdgcn_rcpf(1.f + __expf(-v));
}
__device__ __forceinline__ float tanh_fast(float v){
  return 2.f*__builtin_amdgcn_rcpf(1.f + __expf(-2.f*v)) - 1.f;
}

__device__ __forceinline__ unsigned short f2bf(float f){
  unsigned u = __float_as_uint(f);
  u = (u + 0x7FFF + ((u>>16)&1)) >> 16;     // RNE; inputs finite
  return (unsigned short)u;
}
__device__ __forceinline__ float bf2f(unsigned short b){
  return __uint_as_float(((unsigned)b)<<16);
}

// ---------------- prep: swizzle weights into A-fragment order, bf16 hi/lo ----
// A-frag element (mt, kt, lane l, jj):  A[mt*16 + (l&15)][kt*32 + ((l>>4)&3)*8 + jj]
// stored at ((mt*KT + kt)*64 + l)*8 + jj   -> consumer does 1 coalesced b128/lane
extern "C" __global__ void __launch_bounds__(256)
prep_frag(const float* __restrict__ eWih0, const float* __restrict__ eWhh0,
          const float* __restrict__ eWih1, const float* __restrict__ eWhh1,
          const float* __restrict__ dWih0, const float* __restrict__ dWhh0,
          const float* __restrict__ dWih1, const float* __restrict__ dWhh1,
          unsigned short* __restrict__ ws)
{
  const int idx = blockIdx.x*256 + threadIdx.x;   // one thread -> one (hi,lo) pair
  int i2, hi_base, lo_base, KT;
  const float* Wa; const float* Wb;
  if (idx < L0_SZ)                { i2=idx;                 hi_base=ENC0_HI; lo_base=ENC0_LO; Wa=eWhh0; Wb=eWih0; KT=5; }
  else if (idx < L0_SZ+L1_SZ)     { i2=idx-L0_SZ;           hi_base=ENC1_HI; lo_base=ENC1_LO; Wa=eWih1; Wb=eWhh1; KT=8; }
  else if (idx < 2*L0_SZ+L1_SZ)   { i2=idx-(L0_SZ+L1_SZ);   hi_base=DEC0_HI; lo_base=DEC0_LO; Wa=dWhh0; Wb=dWih0; KT=5; }
  else                            { i2=idx-(2*L0_SZ+L1_SZ); hi_base=DEC1_HI; lo_base=DEC1_LO; Wa=dWih1; Wb=dWhh1; KT=8; }
  const int jj = i2 & 7, l = (i2>>3)&63, tk = i2>>9;
  const int kt = (KT==5) ? (tk%5) : (tk&7);
  const int mt = (KT==5) ? (tk/5) : (tk>>3);
  const int row = mt*16 + (l&15);
  const int k   = kt*32 + ((l>>4)&3)*8 + jj;
  float w;
  if (KT==5) w = (k<128) ? Wa[row*128+k] : ((k<131) ? Wb[row*3 + (k-128)] : 0.f);
  else       w = (k<128) ? Wa[row*128+k] : Wb[row*128 + (k-128)];
  const unsigned short hi = f2bf(w);
  ws[hi_base + i2] = hi;
  ws[lo_base + i2] = f2bf(w - bf2f(hi));
}

// ------- fused LSTM: NB=32/block, 8 waves, 2 BLOCKS PER CU, double-buffered h
// launch_bounds(512,4): 4 waves/SIMD = 2 independent blocks co-resident; the
// blocks drift out of phase naturally, so one block's mv (MFMA) overlaps the
// other's act (VALU) without any source-level scheduling (m114 co-issue).
// Weights: single bf16 (hi only); h in bf16 hi/lo; combos hh + hl (as R9).
// NEW vs R9: (a) h0/h1/xbuf double-buffered by step parity -> the internal
// cell barrier disappears: 2 barriers/step enc, 3 dec (was 4/5).
// (b) XOR swizzle widened n&7 -> n&15: rows n and n+8 no longer alias the
// same 16B slot -> conflict-free b128 h-reads / b64 h-writes.
extern "C" __global__ void __launch_bounds__(TPB, 4)
lstm_mfma(const float* __restrict__ x,
          const unsigned short* __restrict__ wf,
          const float* __restrict__ enc_b0, const float* __restrict__ enc_b1,
          const float* __restrict__ dec_b0, const float* __restrict__ dec_b1,
          const float* __restrict__ fc_W,  const float* __restrict__ fc_b,
          float* __restrict__ out)
{
  // h element (n,k) at n*128 + (((k>>3) ^ (n&15))<<3) + (k&7), per parity buf
  __shared__ unsigned short h0h[2*HSZ], h0l[2*HSZ];
  __shared__ unsigned short h1h[2*HSZ], h1l[2*HSZ];
  __shared__ unsigned short xbh[2*NB*8], xbl[2*NB*8]; // x / mu feedback, 2 parities
  __shared__ unsigned short fcAh[4*512], fcAl[4*512]; // FC weights, A-frag layout
  __shared__ float bias[1024];                         // current phase: [b0 | b1]

  const int tid  = threadIdx.x;
  const int w    = tid>>6, l = tid&63;
  const int quad = (l>>4)&3, n15 = l&15;
  const int b0   = blockIdx.x*NB;

  bias[tid]       = enc_b0[tid];
  bias[512 + tid] = enc_b1[tid];
  for (int i=tid;i<2*HSZ;i+=TPB){ h0h[i]=0; h0l[i]=0; h1h[i]=0; h1l[i]=0; }
  xbh[tid]=0; xbl[tid]=0;                   // 2*NB*8 == 512 == TPB
  if (w < 4){                               // FC weights -> LDS A-frags, kt=w
    short8 vh, vl;
#pragma unroll
    for (int jj=0;jj<8;jj++){
      const float f = (n15<6) ? fc_W[n15*HID + w*32 + quad*8 + jj] : 0.f;
      const unsigned short hi = f2bf(f);
      vh[jj] = (short)hi;
      vl[jj] = (short)f2bf(f - bf2f(hi));
    }
    *(short8*)(fcAh + (w*64+l)*8) = vh;
    *(short8*)(fcAl + (w*64+l)*8) = vl;
  }
  float myfcb[4];
#pragma unroll
  for (int r=0;r<4;r++){
    const int oi = quad*4 + r;
    myfcb[r] = (oi<6) ? fc_b[oi] : 0.f;
  }
  __syncthreads();

  auto write_x = [&](int t, int p){
    if (tid < 96){
      const int n = tid & 31, c = tid >> 5;
      const float v = x[(size_t)(b0+n)*90 + t*3 + c];
      const unsigned short hi = f2bf(v);
      xbh[p*256 + n*8 + c] = hi;
      xbl[p*256 + n*8 + c] = f2bf(v - bf2f(hi));
    }
  };
  write_x(0, 0);
  __syncthreads();

  floatx4 acc[4][2];                 // [gate][nt]; 32 regs
  float c0[2][4], c1[2][4];          // [nt][r]
#pragma unroll
  for (int nt=0;nt<2;nt++)
#pragma unroll
    for (int r=0;r<4;r++){ c0[nt][r]=0.f; c1[nt][r]=0.f; }

  auto zacc = [&]{
    const floatx4 z = {0.f,0.f,0.f,0.f};
#pragma unroll
    for (int g=0;g<4;g++){ acc[g][0]=z; acc[g][1]=z; }
  };

  // acc += A(kt range, single bf16) * B(hi/lo)   combos: hh then hl per acc
  auto mv = [&](const unsigned short* __restrict__ Ahi, int KT,
                int k0, int k1, int kboff,
                const unsigned short* Bh, const unsigned short* Bl){
#pragma unroll 1
    for (int kt=k0; kt<k1; ++kt){
      const int bo = ((((kt-kboff)*4+quad)^n15)<<3);
      short8 bh[2], bl[2];
#pragma unroll
      for (int nt=0;nt<2;nt++){
        const int ro = (nt*16+n15)*128 + bo;
        bh[nt] = *(const short8*)(Bh + ro);
        bl[nt] = *(const short8*)(Bl + ro);
      }
      short8 ah[4];
#pragma unroll
      for (int g=0;g<4;g++){
        const int ao = (((g*8+w)*KT + kt)*64 + l)*8;
        ah[g] = *(const short8*)(Ahi + ao);
      }
#pragma unroll
      for (int g=0;g<4;g++){
        acc[g][0] = __builtin_amdgcn_mfma_f32_16x16x32_bf16(ah[g], bh[0], acc[g][0],0,0,0);
        acc[g][1] = __builtin_amdgcn_mfma_f32_16x16x32_bf16(ah[g], bh[1], acc[g][1],0,0,0);
      }
#pragma unroll
      for (int g=0;g<4;g++){
        acc[g][0] = __builtin_amdgcn_mfma_f32_16x16x32_bf16(ah[g], bl[0], acc[g][0],0,0,0);
        acc[g][1] = __builtin_amdgcn_mfma_f32_16x16x32_bf16(ah[g], bl[1], acc[g][1],0,0,0);
      }
    }
  };

  // kt=4 of layer 0: B comes from xbuf (k=128..135; real data k<131, quad 0 only)
  auto mv_x = [&](const unsigned short* __restrict__ Ahi,
                  const unsigned short* Xh, const unsigned short* Xl){
    const short8 z8 = {0,0,0,0,0,0,0,0};
    short8 bh[2]={z8,z8}, bl[2]={z8,z8};
    if (quad==0){
#pragma unroll
      for (int nt=0;nt<2;nt++){
        const int ro = (nt*16+n15)*8;
        bh[nt] = *(const short8*)(Xh + ro);
        bl[nt] = *(const short8*)(Xl + ro);
      }
    }
    short8 ah[4];
#pragma unroll
    for (int g=0;g<4;g++){
      const int ao = (((g*8+w)*5 + 4)*64 + l)*8;
      ah[g] = *(const short8*)(Ahi + ao);
    }
#pragma unroll
    for (int g=0;g<4;g++){
      acc[g][0] = __builtin_amdgcn_mfma_f32_16x16x32_bf16(ah[g], bh[0], acc[g][0],0,0,0);
      acc[g][1] = __builtin_amdgcn_mfma_f32_16x16x32_bf16(ah[g], bh[1], acc[g][1],0,0,0);
    }
#pragma unroll
    for (int g=0;g<4;g++){
      acc[g][0] = __builtin_amdgcn_mfma_f32_16x16x32_bf16(ah[g], bl[0], acc[g][0],0,0,0);
      acc[g][1] = __builtin_amdgcn_mfma_f32_16x16x32_bf16(ah[g], bl[1], acc[g][1],0,0,0);
    }
  };

  // activations + packed b64 h-writes to the WRITE-parity buffer.
  // No internal barrier: in-interval readers touch the other parity only.
  auto cell = [&](float (&cst)[2][4], int boff,
                  unsigned short* Hh, unsigned short* Hl){
    float hv[2][4];
#pragma unroll
    for (int nt=0;nt<2;nt++)
#pragma unroll
      for (int r=0;r<4;r++){
        const int j = w*16 + quad*4 + r;
        const float i_ = sigm(acc[0][nt][r]      + bias[boff       + j]);
        const float f_ = sigm(acc[1][nt][r]      + bias[boff + 128 + j]);
        const float g_ = tanh_fast(acc[2][nt][r] + bias[boff + 256 + j]);
        const float o_ = sigm(acc[3][nt][r]      + bias[boff + 384 + j]);
        const float c  = f_*cst[nt][r] + i_*g_;
        cst[nt][r] = c;
        hv[nt][r]  = o_*tanh_fast(c);
      }
#pragma unroll
    for (int nt=0;nt<2;nt++){
      const int jb = w*2 + (quad>>1);              // j>>3
      const int n  = nt*16 + n15;
      const int base = n*128 + ((jb ^ n15)<<3) + ((quad&1)<<2);
      ushort4v ph, pl;
#pragma unroll
      for (int r=0;r<4;r++){
        const unsigned short hi = f2bf(hv[nt][r]);
        ph[r] = hi;
        pl[r] = f2bf(hv[nt][r] - bf2f(hi));
      }
      *(ushort4v*)(Hh + base) = ph;                // ds_write_b64
      *(ushort4v*)(Hl + base) = pl;
    }
  };

  // FC head via MFMA: waves 0-1 handle rows n = w*16 .. w*16+15
  // C layout: col=lane&15 -> n, row=quad*4+r -> oi (0..5 used)
  auto fc = [&](int t, const unsigned short* Hh1, const unsigned short* Hl1, int xp){
    if (w < 2){
      floatx4 fa = {0.f,0.f,0.f,0.f};
#pragma unroll
      for (int kt=0;kt<4;kt++){
        const short8 ah = *(const short8*)(fcAh + (kt*64+l)*8);
        const short8 al = *(const short8*)(fcAl + (kt*64+l)*8);
        const int bo = (((kt*4+quad)^n15)<<3);
        const int ro = (w*16+n15)*128 + bo;
        const short8 bh = *(const short8*)(Hh1 + ro);
        const short8 bl = *(const short8*)(Hl1 + ro);
        fa = __builtin_amdgcn_mfma_f32_16x16x32_bf16(ah, bh, fa,0,0,0);
        fa = __builtin_amdgcn_mfma_f32_16x16x32_bf16(ah, bl, fa,0,0,0);
        fa = __builtin_amdgcn_mfma_f32_16x16x32_bf16(al, bh, fa,0,0,0);
      }
      const int n = w*16 + n15;
      const size_t off = (size_t)(b0+n)*90 + (size_t)t*3;
      if (quad == 0){
#pragma unroll
        for (int r=0;r<4;r++){
          const float s = fa[r] + myfcb[r];
          if (r < 3){
            out[off + r] = s;                       // mu
            const unsigned short hi = f2bf(s);      // feed mu back as next x
            xbh[xp*256 + n*8 + r] = hi;
            xbl[xp*256 + n*8 + r] = f2bf(s - bf2f(hi));
          } else {
            out[MU_OFF + off] = s;                  // logvar[0]
          }
        }
      } else if (quad == 1){
#pragma unroll
        for (int r=0;r<2;r++)
          out[MU_OFF + off + 1 + r] = fa[r] + myfcb[r];  // logvar[1,2]
      }
    }
  };

  // -------------------- encoder: 2 barriers/step --------------------
  // step t: read parity ra = t&1, write parity wa = ra^1 (h and xbuf alike)
#pragma unroll 1
  for (int t=0; t<TSTEPS; ++t){
    const int ra = (t&1)*HSZ,  wa = HSZ - ra;
    const int xr = (t&1)*256;
    // phase A: reads h0[ra], xb[ra]; writes h0[wa], xb[wa]
    zacc();
    mv  (wf+ENC0_HI, 5, 0, 4, 0, h0h+ra, h0l+ra);
    mv_x(wf+ENC0_HI, xbh+xr, xbl+xr);
    cell(c0, 0, h0h+wa, h0l+wa);
    if (t+1 < TSTEPS) write_x(t+1, (t+1)&1);
    __syncthreads();                   // h0(t), x(t+1) visible
    // phase E: reads h0[wa], h1[ra]; writes h1[wa]
    zacc();
    mv(wf+ENC1_HI, 8, 0, 4, 0, h0h+wa, h0l+wa);
    mv(wf+ENC1_HI, 8, 4, 8, 4, h1h+ra, h1l+ra);
    cell(c1, 512, h1h+wa, h1l+wa);
    __syncthreads();                   // h1(t) visible
  }
  // xb[1] still holds x[:,29,:] == decoder's initial input (written at t=28)

  // ---- phase switch: dec biases into LDS ----
  bias[tid]       = dec_b0[tid];
  bias[512 + tid] = dec_b1[tid];
  __syncthreads();

  // -------------------- decoder: 3 barriers/step --------------------
  // h parity continues the enc chain (enc t=29 wrote parity 0; dec t reads t&1).
  // xbuf: dec step t reads xb[(t+1)&1], fc(t) writes xb[t&1].
#pragma unroll 1
  for (int t=0; t<TSTEPS; ++t){
    const int ra = (t&1)*HSZ,  wa = HSZ - ra;
    const int xw = (t&1)*256,  xr = 256 - xw;   // read (t+1)&1, write t&1
    // phase A
    zacc();
    mv  (wf+DEC0_HI, 5, 0, 4, 0, h0h+ra, h0l+ra);
    mv_x(wf+DEC0_HI, xbh+xr, xbl+xr);
    cell(c0, 0, h0h+wa, h0l+wa);
    __syncthreads();                   // h0(t) visible
    // phase E
    zacc();
    mv(wf+DEC1_HI, 8, 0, 4, 0, h0h+wa, h0l+wa);
    mv(wf+DEC1_HI, 8, 4, 8, 4, h1h+ra, h1l+ra);
    cell(c1, 512, h1h+wa, h1l+wa);
    __syncthreads();                   // h1(t) visible
    // FC phase
    fc(t, h1h+wa, h1l+wa, t&1);
    __syncthreads();                   // xb(t+1 input) visible
  }
}

extern "C" void kernel_launch(void* const* d_in, const int* in_sizes, int n_in,
                              void* d_out, int out_size, void* d_ws, size_t ws_size,
                              hipStream_t stream) {
  const float* x        = (const float*)d_in[0];
  const float* enc_Wih0 = (const float*)d_in[1];
  const float* enc_Whh0 = (const float*)d_in[2];
  const float* enc_b0   = (const float*)d_in[3];
  const float* enc_Wih1 = (const float*)d_in[4];
  const float* enc_Whh1 = (const float*)d_in[5];
  const float* enc_b1   = (const float*)d_in[6];
  const float* dec_Wih0 = (const float*)d_in[7];
  const float* dec_Whh0 = (const float*)d_in[8];
  const float* dec_b0   = (const float*)d_in[9];
  const float* dec_Wih1 = (const float*)d_in[10];
  const float* dec_Whh1 = (const float*)d_in[11];
  const float* dec_b1   = (const float*)d_in[12];
  const float* fc_W     = (const float*)d_in[13];
  const float* fc_b     = (const float*)d_in[14];
  unsigned short* ws = (unsigned short*)d_ws;
  float* out = (float*)d_out;

  // 425,984 (hi,lo) pairs -> exactly 1664 blocks of 256
  prep_frag<<<1664, 256, 0, stream>>>(
      enc_Wih0, enc_Whh0, enc_Wih1, enc_Whh1,
      dec_Wih0, dec_Whh0, dec_Wih1, dec_Whh1, ws);

  lstm_mfma<<<NBLK, TPB, 0, stream>>>(
      x, ws, enc_b0, enc_b1, dec_b0, dec_b1, fc_W, fc_b, out);
}

// Round 11
// 2657.180 us; speedup vs baseline: 6.7964x; 1.2313x over previous
//
#include <hip/hip_runtime.h>
#include <cstdint>

typedef short short8  __attribute__((ext_vector_type(8)));
typedef unsigned short ushort4v __attribute__((ext_vector_type(4)));
typedef float floatx4 __attribute__((ext_vector_type(4)));

#define HID    128
#define NB     32
#define TPB    512
#define NBLK   2048          // 65536 / 32
#define TSTEPS 30
#define MU_OFF 5898240       // 65536*30*3
#define HSZ    4096          // NB*128: one h parity buffer (bf16 units)

// ws layout (bf16 units): A-fragment-swizzled weight arrays, hi then lo per set
// (lo arrays still produced by prep; the LSTM kernel reads only the hi set)
#define L0_SZ  81920         // 512*160  (K-ext: [Whh(128)|Wih0(3)|0(29)])
#define L1_SZ  131072        // 512*256  (K-ext: [Wih1(128)|Whh1(128)])
#define ENC0_HI 0
#define ENC0_LO 81920
#define ENC1_HI 163840
#define ENC1_LO 294912
#define DEC0_HI 425984
#define DEC0_LO 507904
#define DEC1_HI 589824
#define DEC1_LO 720896

// v_rcp_f32 (~1 ulp) instead of the IEEE div chain
__device__ __forceinline__ float sigm(float v){
  return __builtin_amdgcn_rcpf(1.f + __expf(-v));
}
__device__ __forceinline__ float tanh_fast(float v){
  return 2.f*__builtin_amdgcn_rcpf(1.f + __expf(-2.f*v)) - 1.f;
}

__device__ __forceinline__ unsigned short f2bf(float f){
  unsigned u = __float_as_uint(f);
  u = (u + 0x7FFF + ((u>>16)&1)) >> 16;     // RNE; inputs finite
  return (unsigned short)u;
}
__device__ __forceinline__ float bf2f(unsigned short b){
  return __uint_as_float(((unsigned)b)<<16);
}

// ---------------- prep: swizzle weights into A-fragment order, bf16 hi/lo ----
// A-frag element (mt, kt, lane l, jj):  A[mt*16 + (l&15)][kt*32 + ((l>>4)&3)*8 + jj]
// stored at ((mt*KT + kt)*64 + l)*8 + jj   -> consumer does 1 coalesced b128/lane
extern "C" __global__ void __launch_bounds__(256)
prep_frag(const float* __restrict__ eWih0, const float* __restrict__ eWhh0,
          const float* __restrict__ eWih1, const float* __restrict__ eWhh1,
          const float* __restrict__ dWih0, const float* __restrict__ dWhh0,
          const float* __restrict__ dWih1, const float* __restrict__ dWhh1,
          unsigned short* __restrict__ ws)
{
  const int idx = blockIdx.x*256 + threadIdx.x;   // one thread -> one (hi,lo) pair
  int i2, hi_base, lo_base, KT;
  const float* Wa; const float* Wb;
  if (idx < L0_SZ)                { i2=idx;                 hi_base=ENC0_HI; lo_base=ENC0_LO; Wa=eWhh0; Wb=eWih0; KT=5; }
  else if (idx < L0_SZ+L1_SZ)     { i2=idx-L0_SZ;           hi_base=ENC1_HI; lo_base=ENC1_LO; Wa=eWih1; Wb=eWhh1; KT=8; }
  else if (idx < 2*L0_SZ+L1_SZ)   { i2=idx-(L0_SZ+L1_SZ);   hi_base=DEC0_HI; lo_base=DEC0_LO; Wa=dWhh0; Wb=dWih0; KT=5; }
  else                            { i2=idx-(2*L0_SZ+L1_SZ); hi_base=DEC1_HI; lo_base=DEC1_LO; Wa=dWih1; Wb=dWhh1; KT=8; }
  const int jj = i2 & 7, l = (i2>>3)&63, tk = i2>>9;
  const int kt = (KT==5) ? (tk%5) : (tk&7);
  const int mt = (KT==5) ? (tk/5) : (tk>>3);
  const int row = mt*16 + (l&15);
  const int k   = kt*32 + ((l>>4)&3)*8 + jj;
  float w;
  if (KT==5) w = (k<128) ? Wa[row*128+k] : ((k<131) ? Wb[row*3 + (k-128)] : 0.f);
  else       w = (k<128) ? Wa[row*128+k] : Wb[row*128 + (k-128)];
  const unsigned short hi = f2bf(w);
  ws[hi_base + i2] = hi;
  ws[lo_base + i2] = f2bf(w - bf2f(hi));
}

// ------- fused LSTM: NB=32/block, 8 waves, 2 blocks/CU, h in plain bf16 -----
// 2 co-resident blocks drift out of phase -> cross-block MFMA||VALU overlap
// (m114), confirmed R9/R10 (busy-sum 115%).
// NEW vs R10: h stored as single RNE bf16 (h_lo dropped) -> mv uses ONE combo
// (MFMA count ~halved), act packs only hi, h LDS halves. Weights stay hi-only
// (R9-verified). xbuf (mu feedback) and fcW keep hi/lo. Double-buffered h and
// the n&15 conflict-free swizzle retained from R10.
extern "C" __global__ void __launch_bounds__(TPB, 4)
lstm_mfma(const float* __restrict__ x,
          const unsigned short* __restrict__ wf,
          const float* __restrict__ enc_b0, const float* __restrict__ enc_b1,
          const float* __restrict__ dec_b0, const float* __restrict__ dec_b1,
          const float* __restrict__ fc_W,  const float* __restrict__ fc_b,
          float* __restrict__ out)
{
  // h element (n,k) at n*128 + (((k>>3) ^ (n&15))<<3) + (k&7), per parity buf
  __shared__ unsigned short h0h[2*HSZ];
  __shared__ unsigned short h1h[2*HSZ];
  __shared__ unsigned short xbh[2*NB*8], xbl[2*NB*8]; // x / mu feedback, 2 parities
  __shared__ unsigned short fcAh[4*512], fcAl[4*512]; // FC weights, A-frag layout
  __shared__ float bias[1024];                         // current phase: [b0 | b1]

  const int tid  = threadIdx.x;
  const int w    = tid>>6, l = tid&63;
  const int quad = (l>>4)&3, n15 = l&15;
  const int b0   = blockIdx.x*NB;

  bias[tid]       = enc_b0[tid];
  bias[512 + tid] = enc_b1[tid];
  for (int i=tid;i<2*HSZ;i+=TPB){ h0h[i]=0; h1h[i]=0; }
  xbh[tid]=0; xbl[tid]=0;                   // 2*NB*8 == 512 == TPB
  if (w < 4){                               // FC weights -> LDS A-frags, kt=w
    short8 vh, vl;
#pragma unroll
    for (int jj=0;jj<8;jj++){
      const float f = (n15<6) ? fc_W[n15*HID + w*32 + quad*8 + jj] : 0.f;
      const unsigned short hi = f2bf(f);
      vh[jj] = (short)hi;
      vl[jj] = (short)f2bf(f - bf2f(hi));
    }
    *(short8*)(fcAh + (w*64+l)*8) = vh;
    *(short8*)(fcAl + (w*64+l)*8) = vl;
  }
  float myfcb[4];
#pragma unroll
  for (int r=0;r<4;r++){
    const int oi = quad*4 + r;
    myfcb[r] = (oi<6) ? fc_b[oi] : 0.f;
  }
  __syncthreads();

  auto write_x = [&](int t, int p){
    if (tid < 96){
      const int n = tid & 31, c = tid >> 5;
      const float v = x[(size_t)(b0+n)*90 + t*3 + c];
      const unsigned short hi = f2bf(v);
      xbh[p*256 + n*8 + c] = hi;
      xbl[p*256 + n*8 + c] = f2bf(v - bf2f(hi));
    }
  };
  write_x(0, 0);
  __syncthreads();

  floatx4 acc[4][2];                 // [gate][nt]; 32 regs
  float c0[2][4], c1[2][4];          // [nt][r]
#pragma unroll
  for (int nt=0;nt<2;nt++)
#pragma unroll
    for (int r=0;r<4;r++){ c0[nt][r]=0.f; c1[nt][r]=0.f; }

  auto zacc = [&]{
    const floatx4 z = {0.f,0.f,0.f,0.f};
#pragma unroll
    for (int g=0;g<4;g++){ acc[g][0]=z; acc[g][1]=z; }
  };

  // acc += A(kt range, bf16) * B(h, bf16): single combo per kt
  auto mv = [&](const unsigned short* __restrict__ Ahi, int KT,
                int k0, int k1, int kboff,
                const unsigned short* Bh){
#pragma unroll 1
    for (int kt=k0; kt<k1; ++kt){
      const int bo = ((((kt-kboff)*4+quad)^n15)<<3);
      short8 bh[2];
#pragma unroll
      for (int nt=0;nt<2;nt++){
        const int ro = (nt*16+n15)*128 + bo;
        bh[nt] = *(const short8*)(Bh + ro);
      }
      short8 ah[4];
#pragma unroll
      for (int g=0;g<4;g++){
        const int ao = (((g*8+w)*KT + kt)*64 + l)*8;
        ah[g] = *(const short8*)(Ahi + ao);
      }
#pragma unroll
      for (int g=0;g<4;g++){
        acc[g][0] = __builtin_amdgcn_mfma_f32_16x16x32_bf16(ah[g], bh[0], acc[g][0],0,0,0);
        acc[g][1] = __builtin_amdgcn_mfma_f32_16x16x32_bf16(ah[g], bh[1], acc[g][1],0,0,0);
      }
    }
  };

  // kt=4 of layer 0: B comes from xbuf (hi/lo kept; real data k<131, quad 0 only)
  auto mv_x = [&](const unsigned short* __restrict__ Ahi,
                  const unsigned short* Xh, const unsigned short* Xl){
    const short8 z8 = {0,0,0,0,0,0,0,0};
    short8 bh[2]={z8,z8}, bl[2]={z8,z8};
    if (quad==0){
#pragma unroll
      for (int nt=0;nt<2;nt++){
        const int ro = (nt*16+n15)*8;
        bh[nt] = *(const short8*)(Xh + ro);
        bl[nt] = *(const short8*)(Xl + ro);
      }
    }
    short8 ah[4];
#pragma unroll
    for (int g=0;g<4;g++){
      const int ao = (((g*8+w)*5 + 4)*64 + l)*8;
      ah[g] = *(const short8*)(Ahi + ao);
    }
#pragma unroll
    for (int g=0;g<4;g++){
      acc[g][0] = __builtin_amdgcn_mfma_f32_16x16x32_bf16(ah[g], bh[0], acc[g][0],0,0,0);
      acc[g][1] = __builtin_amdgcn_mfma_f32_16x16x32_bf16(ah[g], bh[1], acc[g][1],0,0,0);
    }
#pragma unroll
    for (int g=0;g<4;g++){
      acc[g][0] = __builtin_amdgcn_mfma_f32_16x16x32_bf16(ah[g], bl[0], acc[g][0],0,0,0);
      acc[g][1] = __builtin_amdgcn_mfma_f32_16x16x32_bf16(ah[g], bl[1], acc[g][1],0,0,0);
    }
  };

  // activations + packed b64 h-writes (hi only) to the WRITE-parity buffer.
  // No internal barrier: in-interval readers touch the other parity only.
  auto cell = [&](float (&cst)[2][4], int boff, unsigned short* Hh){
    float hv[2][4];
#pragma unroll
    for (int nt=0;nt<2;nt++)
#pragma unroll
      for (int r=0;r<4;r++){
        const int j = w*16 + quad*4 + r;
        const float i_ = sigm(acc[0][nt][r]      + bias[boff       + j]);
        const float f_ = sigm(acc[1][nt][r]      + bias[boff + 128 + j]);
        const float g_ = tanh_fast(acc[2][nt][r] + bias[boff + 256 + j]);
        const float o_ = sigm(acc[3][nt][r]      + bias[boff + 384 + j]);
        const float c  = f_*cst[nt][r] + i_*g_;
        cst[nt][r] = c;
        hv[nt][r]  = o_*tanh_fast(c);
      }
#pragma unroll
    for (int nt=0;nt<2;nt++){
      const int jb = w*2 + (quad>>1);              // j>>3
      const int n  = nt*16 + n15;
      const int base = n*128 + ((jb ^ n15)<<3) + ((quad&1)<<2);
      ushort4v ph;
#pragma unroll
      for (int r=0;r<4;r++) ph[r] = f2bf(hv[nt][r]);
      *(ushort4v*)(Hh + base) = ph;                // ds_write_b64
    }
  };

  // FC head via MFMA: waves 0-1 handle rows n = w*16 .. w*16+15
  // B = h1 (bf16); combos: Whi*B + Wlo*B
  auto fc = [&](int t, const unsigned short* Hh1, int xp){
    if (w < 2){
      floatx4 fa = {0.f,0.f,0.f,0.f};
#pragma unroll
      for (int kt=0;kt<4;kt++){
        const short8 ah = *(const short8*)(fcAh + (kt*64+l)*8);
        const short8 al = *(const short8*)(fcAl + (kt*64+l)*8);
        const int bo = (((kt*4+quad)^n15)<<3);
        const int ro = (w*16+n15)*128 + bo;
        const short8 bh = *(const short8*)(Hh1 + ro);
        fa = __builtin_amdgcn_mfma_f32_16x16x32_bf16(ah, bh, fa,0,0,0);
        fa = __builtin_amdgcn_mfma_f32_16x16x32_bf16(al, bh, fa,0,0,0);
      }
      const int n = w*16 + n15;
      const size_t off = (size_t)(b0+n)*90 + (size_t)t*3;
      if (quad == 0){
#pragma unroll
        for (int r=0;r<4;r++){
          const float s = fa[r] + myfcb[r];
          if (r < 3){
            out[off + r] = s;                       // mu
            const unsigned short hi = f2bf(s);      // feed mu back as next x
            xbh[xp*256 + n*8 + r] = hi;
            xbl[xp*256 + n*8 + r] = f2bf(s - bf2f(hi));
          } else {
            out[MU_OFF + off] = s;                  // logvar[0]
          }
        }
      } else if (quad == 1){
#pragma unroll
        for (int r=0;r<2;r++)
          out[MU_OFF + off + 1 + r] = fa[r] + myfcb[r];  // logvar[1,2]
      }
    }
  };

  // -------------------- encoder: 2 barriers/step --------------------
  // step t: read parity ra = t&1, write parity wa = ra^1 (h and xbuf alike)
#pragma unroll 1
  for (int t=0; t<TSTEPS; ++t){
    const int ra = (t&1)*HSZ,  wa = HSZ - ra;
    const int xr = (t&1)*256;
    // phase A: reads h0[ra], xb[ra]; writes h0[wa], xb[wa]
    zacc();
    mv  (wf+ENC0_HI, 5, 0, 4, 0, h0h+ra);
    mv_x(wf+ENC0_HI, xbh+xr, xbl+xr);
    cell(c0, 0, h0h+wa);
    if (t+1 < TSTEPS) write_x(t+1, (t+1)&1);
    __syncthreads();                   // h0(t), x(t+1) visible
    // phase E: reads h0[wa], h1[ra]; writes h1[wa]
    zacc();
    mv(wf+ENC1_HI, 8, 0, 4, 0, h0h+wa);
    mv(wf+ENC1_HI, 8, 4, 8, 4, h1h+ra);
    cell(c1, 512, h1h+wa);
    __syncthreads();                   // h1(t) visible
  }
  // xb[1] still holds x[:,29,:] == decoder's initial input (written at t=28)

  // ---- phase switch: dec biases into LDS ----
  bias[tid]       = dec_b0[tid];
  bias[512 + tid] = dec_b1[tid];
  __syncthreads();

  // -------------------- decoder: 3 barriers/step --------------------
  // h parity continues the enc chain (enc t=29 wrote parity 0; dec t reads t&1).
  // xbuf: dec step t reads xb[(t+1)&1], fc(t) writes xb[t&1].
#pragma unroll 1
  for (int t=0; t<TSTEPS; ++t){
    const int ra = (t&1)*HSZ,  wa = HSZ - ra;
    const int xw = (t&1)*256,  xr = 256 - xw;   // read (t+1)&1, write t&1
    // phase A
    zacc();
    mv  (wf+DEC0_HI, 5, 0, 4, 0, h0h+ra);
    mv_x(wf+DEC0_HI, xbh+xr, xbl+xr);
    cell(c0, 0, h0h+wa);
    __syncthreads();                   // h0(t) visible
    // phase E
    zacc();
    mv(wf+DEC1_HI, 8, 0, 4, 0, h0h+wa);
    mv(wf+DEC1_HI, 8, 4, 8, 4, h1h+ra);
    cell(c1, 512, h1h+wa);
    __syncthreads();                   // h1(t) visible
    // FC phase
    fc(t, h1h+wa, t&1);
    __syncthreads();                   // xb(t+1 input) visible
  }
}

extern "C" void kernel_launch(void* const* d_in, const int* in_sizes, int n_in,
                              void* d_out, int out_size, void* d_ws, size_t ws_size,
                              hipStream_t stream) {
  const float* x        = (const float*)d_in[0];
  const float* enc_Wih0 = (const float*)d_in[1];
  const float* enc_Whh0 = (const float*)d_in[2];
  const float* enc_b0   = (const float*)d_in[3];
  const float* enc_Wih1 = (const float*)d_in[4];
  const float* enc_Whh1 = (const float*)d_in[5];
  const float* enc_b1   = (const float*)d_in[6];
  const float* dec_Wih0 = (const float*)d_in[7];
  const float* dec_Whh0 = (const float*)d_in[8];
  const float* dec_b0   = (const float*)d_in[9];
  const float* dec_Wih1 = (const float*)d_in[10];
  const float* dec_Whh1 = (const float*)d_in[11];
  const float* dec_b1   = (const float*)d_in[12];
  const float* fc_W     = (const float*)d_in[13];
  const float* fc_b     = (const float*)d_in[14];
  unsigned short* ws = (unsigned short*)d_ws;
  float* out = (float*)d_out;

  // 425,984 (hi,lo) pairs -> exactly 1664 blocks of 256
  prep_frag<<<1664, 256, 0, stream>>>(
      enc_Wih0, enc_Whh0, enc_Wih1, enc_Whh1,
      dec_Wih0, dec_Whh0, dec_Wih1, dec_Whh1, ws);

  lstm_mfma<<<NBLK, TPB, 0, stream>>>(
      x, ws, enc_b0, enc_b1, dec_b0, dec_b1, fc_W, fc_b, out);
}